// Round 2
// baseline (460.472 us; speedup 1.0000x reference)
//
#include <hip/hip_runtime.h>
#include <hip/hip_bf16.h>

// Problem dims
#define S_DIM 512
#define I_DIM 384
#define CM 64
#define CZ 128
#define H_DIM 8
#define C_DIM 32
#define HC 256
#define II (I_DIM*I_DIM)      // 147456

typedef short bf16x8 __attribute__((ext_vector_type(8)));
typedef float f32x4 __attribute__((ext_vector_type(4)));

__device__ __forceinline__ float s2f(short s) {
    unsigned int u = ((unsigned int)(unsigned short)s) << 16;
    float f; __builtin_memcpy(&f, &u, 4); return f;
}
__device__ __forceinline__ short f2bf(float f) {
    __hip_bfloat16 h = __float2bfloat16(f);
    short r; __builtin_memcpy(&r, &h, 2); return r;
}

// async global->LDS, 16B per lane. LDS dest is wave-uniform base + lane*16.
// Global source address is per-lane (enables slot-major staging).
__device__ __forceinline__ void glds16(const short* g, short* l) {
    __builtin_amdgcn_global_load_lds(
        (const __attribute__((address_space(1))) void*)g,
        (__attribute__((address_space(3))) void*)l, 16, 0, 0);
}

// ---------------------------------------------------------------------------
// K1: pair LN (CZ=128) + W_bias -> bias[h][i][j] (fp32). One wave per (i,j).
// ---------------------------------------------------------------------------
__global__ __launch_bounds__(256) void k_pair_ln_bias(
    const float* __restrict__ pair, const float* __restrict__ g,
    const float* __restrict__ b, const float* __restrict__ Wb,
    float* __restrict__ bias)
{
    __shared__ float xs[4][CZ];
    __shared__ float WbT[H_DIM*132];
    const int tid = threadIdx.x;
    const int wv = tid >> 6, lane = tid & 63;
    const int ij = blockIdx.x*4 + wv;

    {
        float4 q = *(const float4*)(Wb + tid*4);
        int m = tid*4;
        WbT[(m&7)*132 + (m>>3)]     = q.x;
        WbT[((m+1)&7)*132 + ((m+1)>>3)] = q.y;
        WbT[((m+2)&7)*132 + ((m+2)>>3)] = q.z;
        WbT[((m+3)&7)*132 + ((m+3)>>3)] = q.w;
    }

    float2 x2 = *(const float2*)(pair + (size_t)ij*CZ + lane*2);
    float s1 = x2.x + x2.y;
    float s2 = x2.x*x2.x + x2.y*x2.y;
#pragma unroll
    for (int off = 32; off > 0; off >>= 1) {
        s1 += __shfl_xor(s1, off, 64);
        s2 += __shfl_xor(s2, off, 64);
    }
    float mu = s1 * (1.f/CZ);
    float var = s2 * (1.f/CZ) - mu*mu;
    float rs = rsqrtf(var + 1e-5f);
    xs[wv][lane*2]   = (x2.x - mu)*rs*g[lane*2]   + b[lane*2];
    xs[wv][lane*2+1] = (x2.y - mu)*rs*g[lane*2+1] + b[lane*2+1];
    __syncthreads();

    const int h = lane >> 3, seg = lane & 7;
    float p = 0.f;
#pragma unroll
    for (int jj = 0; jj < 16; jj++) {
        int c = seg + jj*8;
        p += xs[wv][c] * WbT[h*132 + c];
    }
    p += __shfl_down(p, 4, 64);
    p += __shfl_down(p, 2, 64);
    p += __shfl_down(p, 1, 64);
    if (seg == 0) bias[(size_t)h*II + ij] = p;
}

// ---------------------------------------------------------------------------
// K2: softmax over j for each (i,h) -> w[h][i][j] (bf16).
// ---------------------------------------------------------------------------
__global__ __launch_bounds__(384) void k_softmax(
    const float* __restrict__ bias, short* __restrict__ w)
{
    int blk = blockIdx.x;
    int i = blk >> 3, h = blk & 7;
    int j = threadIdx.x;
    float x = bias[(size_t)h*II + i*I_DIM + j];
    float m = x;
#pragma unroll
    for (int off = 32; off > 0; off >>= 1) m = fmaxf(m, __shfl_xor(m, off, 64));
    __shared__ float red[6];
    int wv = j >> 6;
    if ((j & 63) == 0) red[wv] = m;
    __syncthreads();
    m = red[0];
#pragma unroll
    for (int k = 1; k < 6; k++) m = fmaxf(m, red[k]);
    float e = __expf(x - m);
    float s = e;
#pragma unroll
    for (int off = 32; off > 0; off >>= 1) s += __shfl_xor(s, off, 64);
    __syncthreads();
    if ((j & 63) == 0) red[wv] = s;
    __syncthreads();
    s = 0.f;
#pragma unroll
    for (int k = 0; k < 6; k++) s += red[k];
    w[(size_t)h*II + i*I_DIM + j] = f2bf(e / s);
}

// ---------------------------------------------------------------------------
// K3b: fp32 weights -> B^T bf16 layouts. Wt[512][64], Wot[64][256].
// ---------------------------------------------------------------------------
__global__ __launch_bounds__(256) void k_prep_w(
    const float* __restrict__ Wv, const float* __restrict__ Wg,
    const float* __restrict__ Wo,
    short* __restrict__ Wt, short* __restrict__ Wot)
{
    int idx = blockIdx.x*256 + threadIdx.x;
    if (idx < 512*64) {
        int n = idx >> 6, k = idx & 63;
        Wt[idx] = f2bf((n < HC) ? Wv[k*HC + n] : Wg[k*HC + (n - HC)]);
    } else {
        int q = idx - 512*64;
        int n = q >> 8, k = q & 255;
        Wot[q] = f2bf(Wo[k*64 + n]);
    }
}

// ---------------------------------------------------------------------------
// K4 v2: fused msa-LN + v/gate GEMM [64 x 512 tile].
//  - Bs slot-major [4 slots][512 rows][8]: b128 reads are 2-way banked (free)
//    instead of 8-way (stride-64B).  Staged via per-lane global addresses.
//  - kt=0 stage hoisted above LN block: Wt load latency hides under LN VALU.
// ---------------------------------------------------------------------------
__global__ __launch_bounds__(256) void k4_ln_vgate(
    const float* __restrict__ msa_c,
    const float* __restrict__ gm, const float* __restrict__ bm,
    const short* __restrict__ Wt,
    short* __restrict__ v_t, short* __restrict__ gate)
{
    __shared__ alignas(16) short lds[20992];     // 41984 B
    short* As = lds;            // [64][72] staging (LN output)
    short* Bs = lds + 4608;     // slot-major [4][512][8]
    short* T  = lds;            // epilogue transpose [256][72] (reuse)

    const int tid = threadIdx.x;
    const int wave = tid >> 6;
    const int lane = tid & 63;
    const int pm = blockIdx.y;

    // stage Bs tile kt: 32 chunks (slot=wave, rowgroup=c2), per-lane gsrc
    auto stage_b = [&](int kt) {
#pragma unroll
        for (int c2 = 0; c2 < 8; c2++)
            glds16(Wt + (size_t)(c2*64 + lane)*64 + kt*32 + wave*8,
                   &Bs[(wave*512 + c2*64)*8]);
    };
    stage_b(0);     // flies over the LN block below

    // LN + stage A (4 lanes per row, 16 elems each)
    {
        const int row = tid >> 2;
        const int seg = tid & 3;
        float xf[16], gf[16], bf[16];
        const float* rp = msa_c + (size_t)(pm*64 + row)*CM + seg*16;
#pragma unroll
        for (int q = 0; q < 4; q++) {
            float4 a = *(const float4*)(rp + q*4);
            xf[q*4] = a.x; xf[q*4+1] = a.y; xf[q*4+2] = a.z; xf[q*4+3] = a.w;
            float4 gg = *(const float4*)(gm + seg*16 + q*4);
            gf[q*4] = gg.x; gf[q*4+1] = gg.y; gf[q*4+2] = gg.z; gf[q*4+3] = gg.w;
            float4 bb = *(const float4*)(bm + seg*16 + q*4);
            bf[q*4] = bb.x; bf[q*4+1] = bb.y; bf[q*4+2] = bb.z; bf[q*4+3] = bb.w;
        }
        float s1 = 0.f, s2 = 0.f;
#pragma unroll
        for (int j = 0; j < 16; j++) { s1 += xf[j]; s2 += xf[j]*xf[j]; }
        s1 += __shfl_xor(s1, 1); s2 += __shfl_xor(s2, 1);
        s1 += __shfl_xor(s1, 2); s2 += __shfl_xor(s2, 2);
        float mu = s1 * (1.f/64.f);
        float var = s2 * (1.f/64.f) - mu*mu;
        float rs = rsqrtf(var + 1e-5f);
        bf16x8 o0, o1;
#pragma unroll
        for (int j = 0; j < 8; j++) {
            o0[j] = f2bf((xf[j]   - mu)*rs*gf[j]   + bf[j]);
            o1[j] = f2bf((xf[8+j] - mu)*rs*gf[8+j] + bf[8+j]);
        }
        *(bf16x8*)&As[row*72 + seg*16]     = o0;
        *(bf16x8*)&As[row*72 + seg*16 + 8] = o1;
    }

    const int fr = lane & 15, fq = lane >> 4;
    f32x4 acc[4][8] = {};

    for (int kt = 0; kt < 2; ++kt) {
        __syncthreads();   // covers As ds_writes + Bs async loads (vmcnt0)

        bf16x8 af[4], bfrag[8];
#pragma unroll
        for (int mi = 0; mi < 4; mi++)
            af[mi] = *(const bf16x8*)&As[(mi*16 + fr)*72 + kt*32 + fq*8];
#pragma unroll
        for (int ni = 0; ni < 8; ni++)
            bfrag[ni] = *(const bf16x8*)&Bs[(fq*512 + wave*128 + ni*16 + fr)*8];
#pragma unroll
        for (int mi = 0; mi < 4; mi++)
#pragma unroll
            for (int ni = 0; ni < 8; ni++)
                acc[mi][ni] = __builtin_amdgcn_mfma_f32_16x16x32_bf16(
                    af[mi], bfrag[ni], acc[mi][ni], 0, 0, 0);
        __syncthreads();
        if (kt == 0) stage_b(1);
    }

    // epilogue: C/D layout col=lane&15, row=(lane>>4)*4+reg  [m89/m91]
    const int s_local = pm / 6;
    const int j0 = (pm % 6) * 64;
    if (wave < 2) {
        // v (cols 0..255): pack r-quads into transpose buffer T[cl][72]
#pragma unroll
        for (int mi = 0; mi < 4; mi++)
#pragma unroll
        for (int ni = 0; ni < 8; ni++) {
            int cl = wave*128 + ni*16 + fr;
            short4 pk;
            pk.x = f2bf(acc[mi][ni][0]);
            pk.y = f2bf(acc[mi][ni][1]);
            pk.z = f2bf(acc[mi][ni][2]);
            pk.w = f2bf(acc[mi][ni][3]);
            *(short4*)&T[cl*72 + mi*16 + fq*4] = pk;
        }
    } else {
        // gate (cols 256..511): sigmoid, direct store [row][hc]
#pragma unroll
        for (int mi = 0; mi < 4; mi++)
#pragma unroll
        for (int ni = 0; ni < 8; ni++)
#pragma unroll
        for (int r = 0; r < 4; r++) {
            int rowg = pm*64 + mi*16 + fq*4 + r;
            int col = (wave - 2)*128 + ni*16 + fr;
            gate[(size_t)rowg*HC + col] =
                f2bf(1.f/(1.f + __expf(-acc[mi][ni][r])));
        }
    }
    __syncthreads();
    // coalesced v_t store: 2048 units x 8 shorts (16B)
#pragma unroll
    for (int p = 0; p < 8; p++) {
        int unit = p*256 + tid;
        int cl = unit >> 3, part = unit & 7;
        bf16x8 d = *(const bf16x8*)&T[cl*72 + part*8];
        int h = cl >> 5, cc = cl & 31;
        *(bf16x8*)&v_t[(((size_t)s_local*H_DIM + h)*C_DIM + cc)*I_DIM + j0 + part*8] = d;
    }
}

// ---------------------------------------------------------------------------
// K56 v4: fused einsum + gate-mult + out-projection.
// Grid (2, Sc/2): blockIdx.x = i-half (192 rows), blockIdx.y = s-PAIR.
// Waves 0-1 own s0 (i rows 0-96 / 96-192 of the half), waves 2-3 own s1.
//   -> 12 MFMA/wave/tile (2x v3), w L2 traffic halved, Ob wave-private
//      (no epilogue barriers), and 16 staged chunks/tile = 4/wave (uniform
//      vmcnt counting).
// T4 counted-vmcnt pipeline: raw s_barrier + s_waitcnt vmcnt(4) -- stage for
// tile t+2 issued at iter t, waited 2 iterations later. NEVER drains to 0.
// Slot-major LDS [4 slots][rows][8]: ds_read_b128 2-way banked (free).
// Math/accumulation order identical to v3.
// ---------------------------------------------------------------------------
__global__ __launch_bounds__(256, 2) void k56_einsum_proj(
    const short* __restrict__ w,     // [8][384][384]
    const short* __restrict__ v_t,   // [Sc][8][32][384]
    const short* __restrict__ gate,  // [Sc*384][256]
    const short* __restrict__ Wot,   // [64][256]
    float* __restrict__ out)         // [Sc*384][64]
{
    __shared__ alignas(16) short Ws[2][4*192*8];   // 2 x 12288 B, slot-major
    __shared__ alignas(16) short Vs[2][2][1024];   // 2 x 2s x 2048 B, slot-major
    __shared__ alignas(16) short Ob[4][96*40];     // wave-private, 30720 B
    const int tid = threadIdx.x;                   // total LDS 63488 B
    const int wave = tid >> 6, lane = tid & 63;
    const int fr = lane & 15, fq = lane >> 4;
    const int ibase = blockIdx.x * 192;   // i-half
    const int sp = blockIdx.y;            // s-pair
    const int ms = wave >> 1;             // my s within pair (0/1)
    const int kv = wave & 1;              // wave's role within s
    const int s  = sp*2 + ms;
    const int iw = kv * 96;               // wave's i-offset within half

    const short* vbm = v_t + (size_t)s * H_DIM * C_DIM * I_DIM;

    // stage tile (h_,kt_) into buf: per wave 3 Ws chunks (slot=wave,
    // rowgroups 0..2) + 1 Vs chunk (s=ms, slots 2kv..2kv+1). 4 glds/wave.
    auto stage = [&](int h_, int kt_, int buf) {
        const short* wp = w + (size_t)h_*II + kt_*32 + wave*8;
#pragma unroll
        for (int rg = 0; rg < 3; rg++)
            glds16(wp + (size_t)(ibase + rg*64 + lane)*I_DIM,
                   &Ws[buf][(wave*192 + rg*64)*8]);
        glds16(vbm + (size_t)h_*C_DIM*I_DIM + (lane & 31)*I_DIM + kt_*32
                   + (2*kv + (lane >> 5))*8,
               &Vs[buf][ms][kv*512]);
    };

    f32x4 acc_o[6][4] = {};

    stage(0, 0, 0);
    stage(0, 1, 1);

    for (int h = 0; h < H_DIM; h++) {
        f32x4 acc_e[2][6] = {};
        short4 gv[2][6];
        bf16x8 bw[4];
#pragma unroll
        for (int kt = 0; kt < 12; kt++) {
            const int cb = kt & 1;
            // tile t ready: own 4 oldest loads done (t+1's 4 stay in flight)
            asm volatile("s_waitcnt vmcnt(4)" ::: "memory");
            __builtin_amdgcn_s_barrier();
            __builtin_amdgcn_sched_barrier(0);

            bf16x8 av[2], bwv[6];
#pragma unroll
            for (int mi = 0; mi < 2; mi++)
                av[mi] = *(const bf16x8*)&Vs[cb][ms][(fq*32 + mi*16 + fr)*8];
#pragma unroll
            for (int ni = 0; ni < 6; ni++)
                bwv[ni] = *(const bf16x8*)&Ws[cb][(fq*192 + iw + ni*16 + fr)*8];
            asm volatile("s_waitcnt lgkmcnt(0)" ::: "memory");
            __builtin_amdgcn_s_barrier();          // all waves done reading cb
            __builtin_amdgcn_sched_barrier(0);

            if (kt == 10) {
                // epilogue operand prefetch (older than stage(t+2) -> drained
                // by next iter's vmcnt(4), which is where we want them)
#pragma unroll
                for (int ni = 0; ni < 4; ni++)
                    bw[ni] = *(const bf16x8*)&Wot[(ni*16 + fr)*HC + h*C_DIM + fq*8];
#pragma unroll
                for (int mi = 0; mi < 2; mi++)
#pragma unroll
                for (int ni = 0; ni < 6; ni++)
                    gv[mi][ni] = *(const short4*)&gate[
                        (size_t)(s*I_DIM + ibase + iw + ni*16 + fr)*HC
                        + h*C_DIM + mi*16 + fq*4];
            }
            // issue tile t+2 into cb (flies over MFMA(t) + all of iter t+1)
            if (kt < 10)          stage(h, kt + 2, cb);
            else if (h < 7)       stage(h + 1, kt - 10, cb);

            __builtin_amdgcn_s_setprio(1);
#pragma unroll
            for (int mi = 0; mi < 2; mi++)
#pragma unroll
                for (int ni = 0; ni < 6; ni++)
                    acc_e[mi][ni] = __builtin_amdgcn_mfma_f32_16x16x32_bf16(
                        av[mi], bwv[ni], acc_e[mi][ni], 0, 0, 0);
            __builtin_amdgcn_s_setprio(0);
        }

        // per-h epilogue: gate mult + proj partial. Ob is WAVE-PRIVATE ->
        // no barriers; next-h tiles (staged above) keep flying over this.
        // D layout: c = mi*16 + fq*4 + r, i = ni*16 + fr   [m89/m91]
        short* myOb = Ob[wave];
#pragma unroll
        for (int mi = 0; mi < 2; mi++)
#pragma unroll
        for (int ni = 0; ni < 6; ni++) {
            int row = ni*16 + fr;
            int c0 = mi*16 + fq*4;
            short4 g = gv[mi][ni];
            short4 pk;
            pk.x = f2bf(acc_e[mi][ni][0] * s2f(g.x));
            pk.y = f2bf(acc_e[mi][ni][1] * s2f(g.y));
            pk.z = f2bf(acc_e[mi][ni][2] * s2f(g.z));
            pk.w = f2bf(acc_e[mi][ni][3] * s2f(g.w));
            *(short4*)&myOb[row*40 + c0] = pk;
        }
        bf16x8 ao[6];
#pragma unroll
        for (int mi = 0; mi < 6; mi++)
            ao[mi] = *(const bf16x8*)&myOb[(mi*16 + fr)*40 + fq*8];
        __builtin_amdgcn_s_setprio(1);
#pragma unroll
        for (int mi = 0; mi < 6; mi++)
#pragma unroll
            for (int ni = 0; ni < 4; ni++)
                acc_o[mi][ni] = __builtin_amdgcn_mfma_f32_16x16x32_bf16(
                    ao[mi], bw[ni], acc_o[mi][ni], 0, 0, 0);
        __builtin_amdgcn_s_setprio(0);
    }

    // store out fp32 (this wave's 96 i rows for its s)
#pragma unroll
    for (int mi = 0; mi < 6; mi++)
#pragma unroll
    for (int ni = 0; ni < 4; ni++)
#pragma unroll
    for (int r = 0; r < 4; r++) {
        int i = ibase + iw + mi*16 + fq*4 + r;
        int n = ni*16 + fr;
        out[(size_t)(s*I_DIM + i)*CM + n] = acc_o[mi][ni][r];
    }
}

// ---------------------------------------------------------------------------
extern "C" void kernel_launch(void* const* d_in, const int* in_sizes, int n_in,
                              void* d_out, int out_size, void* d_ws, size_t ws_size,
                              hipStream_t stream)
{
    const float* msa  = (const float*)d_in[0];
    const float* pair = (const float*)d_in[1];
    const float* gm   = (const float*)d_in[2];
    const float* bm   = (const float*)d_in[3];
    const float* gp   = (const float*)d_in[4];
    const float* bp   = (const float*)d_in[5];
    const float* Wv   = (const float*)d_in[6];
    const float* Wb   = (const float*)d_in[7];
    const float* Wg   = (const float*)d_in[8];
    const float* Wo   = (const float*)d_in[9];

    // ws layout: w bf16 [0,2359296) | Wt [2359296,2424832) | Wot [2424832,2457600)
    //            region: bias fp32 overlay (dead after softmax), then v_t+gate
    char* ws = (char*)d_ws;
    short* w    = (short*)ws;
    short* Wt   = (short*)(ws + 2359296);
    short* Wot  = (short*)(ws + 2424832);
    char*  region = ws + 2457600;
    float* bias = (float*)region;

    // Largest S-chunk whose v_t+gate (Sc*393216 B) fits the region.
    size_t avail = (ws_size > 2457600u) ? (ws_size - 2457600u) : 0;
    int Sc = 8;
    const int scs[7] = {512, 256, 128, 64, 32, 16, 8};
    for (int i = 0; i < 7; i++) {
        size_t need = (size_t)scs[i] * 393216u;
        if (need < 4718592u) need = 4718592u;   // region also holds bias
        if (need <= avail) { Sc = scs[i]; break; }
    }
    const int NC = S_DIM / Sc;
    short* v_t  = (short*)region;                            // [Sc][8][32][384]
    short* gate = (short*)(region + (size_t)Sc*196608u);     // [Sc*384][256]

    k_pair_ln_bias<<<dim3(II/4), dim3(256), 0, stream>>>(pair, gp, bp, Wb, bias);
    k_prep_w<<<dim3(192), dim3(256), 0, stream>>>(Wv, Wg, Wo, Wt, Wot);
    k_softmax<<<dim3(I_DIM*H_DIM), dim3(I_DIM), 0, stream>>>(bias, w);

    for (int c = 0; c < NC; c++) {
        size_t in_off = (size_t)c * Sc * I_DIM * CM;

        // K4: fused LN + v/gate GEMM [Sc*384 x 64] @ [64 x 512]
        k4_ln_vgate<<<dim3(1, Sc*6, 1), dim3(256), 0, stream>>>(
            msa + in_off, gm, bm, Wt, v_t, gate);

        // K56 v4: fused einsum + gate + out-projection, (i-half, s-pair) grid
        k56_einsum_proj<<<dim3(2, Sc/2), dim3(256), 0, stream>>>(
            w, v_t, gate, Wot, (float*)d_out + in_off);
    }
}

// Round 3
// 411.246 us; speedup vs baseline: 1.1197x; 1.1197x over previous
//
#include <hip/hip_runtime.h>
#include <hip/hip_bf16.h>

// Problem dims
#define S_DIM 512
#define I_DIM 384
#define CM 64
#define CZ 128
#define H_DIM 8
#define C_DIM 32
#define HC 256
#define II (I_DIM*I_DIM)      // 147456

typedef short bf16x8 __attribute__((ext_vector_type(8)));
typedef float f32x4 __attribute__((ext_vector_type(4)));

__device__ __forceinline__ float s2f(short s) {
    unsigned int u = ((unsigned int)(unsigned short)s) << 16;
    float f; __builtin_memcpy(&f, &u, 4); return f;
}
__device__ __forceinline__ short f2bf(float f) {
    __hip_bfloat16 h = __float2bfloat16(f);
    short r; __builtin_memcpy(&r, &h, 2); return r;
}

// async global->LDS, 16B per lane. LDS dest is wave-uniform base + lane*16.
// Global source address is per-lane (enables swizzled staging).
__device__ __forceinline__ void glds16(const short* g, short* l) {
    __builtin_amdgcn_global_load_lds(
        (const __attribute__((address_space(1))) void*)g,
        (__attribute__((address_space(3))) void*)l, 16, 0, 0);
}

// ---------------------------------------------------------------------------
// K1: pair LN (CZ=128) + W_bias -> bias[h][i][j] (fp32). One wave per (i,j).
// ---------------------------------------------------------------------------
__global__ __launch_bounds__(256) void k_pair_ln_bias(
    const float* __restrict__ pair, const float* __restrict__ g,
    const float* __restrict__ b, const float* __restrict__ Wb,
    float* __restrict__ bias)
{
    __shared__ float xs[4][CZ];
    __shared__ float WbT[H_DIM*132];
    const int tid = threadIdx.x;
    const int wv = tid >> 6, lane = tid & 63;
    const int ij = blockIdx.x*4 + wv;

    {
        float4 q = *(const float4*)(Wb + tid*4);
        int m = tid*4;
        WbT[(m&7)*132 + (m>>3)]     = q.x;
        WbT[((m+1)&7)*132 + ((m+1)>>3)] = q.y;
        WbT[((m+2)&7)*132 + ((m+2)>>3)] = q.z;
        WbT[((m+3)&7)*132 + ((m+3)>>3)] = q.w;
    }

    float2 x2 = *(const float2*)(pair + (size_t)ij*CZ + lane*2);
    float s1 = x2.x + x2.y;
    float s2 = x2.x*x2.x + x2.y*x2.y;
#pragma unroll
    for (int off = 32; off > 0; off >>= 1) {
        s1 += __shfl_xor(s1, off, 64);
        s2 += __shfl_xor(s2, off, 64);
    }
    float mu = s1 * (1.f/CZ);
    float var = s2 * (1.f/CZ) - mu*mu;
    float rs = rsqrtf(var + 1e-5f);
    xs[wv][lane*2]   = (x2.x - mu)*rs*g[lane*2]   + b[lane*2];
    xs[wv][lane*2+1] = (x2.y - mu)*rs*g[lane*2+1] + b[lane*2+1];
    __syncthreads();

    const int h = lane >> 3, seg = lane & 7;
    float p = 0.f;
#pragma unroll
    for (int jj = 0; jj < 16; jj++) {
        int c = seg + jj*8;
        p += xs[wv][c] * WbT[h*132 + c];
    }
    p += __shfl_down(p, 4, 64);
    p += __shfl_down(p, 2, 64);
    p += __shfl_down(p, 1, 64);
    if (seg == 0) bias[(size_t)h*II + ij] = p;
}

// ---------------------------------------------------------------------------
// K2: softmax over j for each (i,h) -> w[h][i][j] (bf16).
// ---------------------------------------------------------------------------
__global__ __launch_bounds__(384) void k_softmax(
    const float* __restrict__ bias, short* __restrict__ w)
{
    int blk = blockIdx.x;
    int i = blk >> 3, h = blk & 7;
    int j = threadIdx.x;
    float x = bias[(size_t)h*II + i*I_DIM + j];
    float m = x;
#pragma unroll
    for (int off = 32; off > 0; off >>= 1) m = fmaxf(m, __shfl_xor(m, off, 64));
    __shared__ float red[6];
    int wv = j >> 6;
    if ((j & 63) == 0) red[wv] = m;
    __syncthreads();
    m = red[0];
#pragma unroll
    for (int k = 1; k < 6; k++) m = fmaxf(m, red[k]);
    float e = __expf(x - m);
    float s = e;
#pragma unroll
    for (int off = 32; off > 0; off >>= 1) s += __shfl_xor(s, off, 64);
    __syncthreads();
    if ((j & 63) == 0) red[wv] = s;
    __syncthreads();
    s = 0.f;
#pragma unroll
    for (int k = 0; k < 6; k++) s += red[k];
    w[(size_t)h*II + i*I_DIM + j] = f2bf(e / s);
}

// ---------------------------------------------------------------------------
// K3b: fp32 weights -> B^T bf16 layouts. Wt[512][64], Wot[64][256].
// ---------------------------------------------------------------------------
__global__ __launch_bounds__(256) void k_prep_w(
    const float* __restrict__ Wv, const float* __restrict__ Wg,
    const float* __restrict__ Wo,
    short* __restrict__ Wt, short* __restrict__ Wot)
{
    int idx = blockIdx.x*256 + threadIdx.x;
    if (idx < 512*64) {
        int n = idx >> 6, k = idx & 63;
        Wt[idx] = f2bf((n < HC) ? Wv[k*HC + n] : Wg[k*HC + (n - HC)]);
    } else {
        int q = idx - 512*64;
        int n = q >> 8, k = q & 255;
        Wot[q] = f2bf(Wo[k*64 + n]);
    }
}

// ---------------------------------------------------------------------------
// K4: fused msa-LN + v/gate GEMM [64 x 512 tile].  (round-0 version, best
// measured; slot-major experiment in r2 regressed ~20us -> reverted)
// ---------------------------------------------------------------------------
__global__ __launch_bounds__(256) void k4_ln_vgate(
    const float* __restrict__ msa_c,
    const float* __restrict__ gm, const float* __restrict__ bm,
    const short* __restrict__ Wt,
    short* __restrict__ v_t, short* __restrict__ gate)
{
    __shared__ alignas(16) short lds[20992];     // 41984 B
    short* As = lds;            // [64][72] staging (LN output)
    short* Bs = lds + 4608;     // [512][32] staging (Wt)
    short* T  = lds;            // epilogue transpose [256][72] (reuse)

    const int tid = threadIdx.x;
    const int wave = tid >> 6;
    const int lane = tid & 63;
    const int pm = blockIdx.y;

    // LN + stage A (4 lanes per row, 16 elems each)
    {
        const int row = tid >> 2;
        const int seg = tid & 3;
        float xf[16], gf[16], bf[16];
        const float* rp = msa_c + (size_t)(pm*64 + row)*CM + seg*16;
#pragma unroll
        for (int q = 0; q < 4; q++) {
            float4 a = *(const float4*)(rp + q*4);
            xf[q*4] = a.x; xf[q*4+1] = a.y; xf[q*4+2] = a.z; xf[q*4+3] = a.w;
            float4 gg = *(const float4*)(gm + seg*16 + q*4);
            gf[q*4] = gg.x; gf[q*4+1] = gg.y; gf[q*4+2] = gg.z; gf[q*4+3] = gg.w;
            float4 bb = *(const float4*)(bm + seg*16 + q*4);
            bf[q*4] = bb.x; bf[q*4+1] = bb.y; bf[q*4+2] = bb.z; bf[q*4+3] = bb.w;
        }
        float s1 = 0.f, s2 = 0.f;
#pragma unroll
        for (int j = 0; j < 16; j++) { s1 += xf[j]; s2 += xf[j]*xf[j]; }
        s1 += __shfl_xor(s1, 1); s2 += __shfl_xor(s2, 1);
        s1 += __shfl_xor(s1, 2); s2 += __shfl_xor(s2, 2);
        float mu = s1 * (1.f/64.f);
        float var = s2 * (1.f/64.f) - mu*mu;
        float rs = rsqrtf(var + 1e-5f);
        bf16x8 o0, o1;
#pragma unroll
        for (int j = 0; j < 8; j++) {
            o0[j] = f2bf((xf[j]   - mu)*rs*gf[j]   + bf[j]);
            o1[j] = f2bf((xf[8+j] - mu)*rs*gf[8+j] + bf[8+j]);
        }
        *(bf16x8*)&As[row*72 + seg*16]     = o0;
        *(bf16x8*)&As[row*72 + seg*16 + 8] = o1;
    }

    const int lr = lane >> 2, lq = lane & 3;
    const int fr = lane & 15, fq = lane >> 4;
    f32x4 acc[4][8] = {};

    for (int kt = 0; kt < 2; ++kt) {
#pragma unroll
        for (int c2 = 0; c2 < 8; c2++) {
            int ch = wave + c2*4;
            glds16(Wt + (ch*16 + lr)*64 + kt*32 + lq*8, &Bs[ch*512]);
        }
        __syncthreads();   // covers As ds_writes (kt=0) + Bs async loads

        bf16x8 af[4], bfrag[8];
#pragma unroll
        for (int mi = 0; mi < 4; mi++)
            af[mi] = *(const bf16x8*)&As[(mi*16 + fr)*72 + kt*32 + fq*8];
#pragma unroll
        for (int ni = 0; ni < 8; ni++)
            bfrag[ni] = *(const bf16x8*)&Bs[(wave*128 + ni*16 + fr)*32 + fq*8];
#pragma unroll
        for (int mi = 0; mi < 4; mi++)
#pragma unroll
            for (int ni = 0; ni < 8; ni++)
                acc[mi][ni] = __builtin_amdgcn_mfma_f32_16x16x32_bf16(
                    af[mi], bfrag[ni], acc[mi][ni], 0, 0, 0);
        __syncthreads();
    }

    // epilogue: C/D layout col=lane&15, row=(lane>>4)*4+reg  [m89/m91]
    const int s_local = pm / 6;
    const int j0 = (pm % 6) * 64;
    if (wave < 2) {
        // v (cols 0..255): pack r-quads into transpose buffer T[cl][72]
#pragma unroll
        for (int mi = 0; mi < 4; mi++)
#pragma unroll
        for (int ni = 0; ni < 8; ni++) {
            int cl = wave*128 + ni*16 + fr;
            short4 pk;
            pk.x = f2bf(acc[mi][ni][0]);
            pk.y = f2bf(acc[mi][ni][1]);
            pk.z = f2bf(acc[mi][ni][2]);
            pk.w = f2bf(acc[mi][ni][3]);
            *(short4*)&T[cl*72 + mi*16 + fq*4] = pk;
        }
    } else {
        // gate (cols 256..511): sigmoid, direct store [row][hc]
#pragma unroll
        for (int mi = 0; mi < 4; mi++)
#pragma unroll
        for (int ni = 0; ni < 8; ni++)
#pragma unroll
        for (int r = 0; r < 4; r++) {
            int rowg = pm*64 + mi*16 + fq*4 + r;
            int col = (wave - 2)*128 + ni*16 + fr;
            gate[(size_t)rowg*HC + col] =
                f2bf(1.f/(1.f + __expf(-acc[mi][ni][r])));
        }
    }
    __syncthreads();
    // coalesced v_t store: 2048 units x 8 shorts (16B)
#pragma unroll
    for (int p = 0; p < 8; p++) {
        int unit = p*256 + tid;
        int cl = unit >> 3, part = unit & 7;
        bf16x8 d = *(const bf16x8*)&T[cl*72 + part*8];
        int h = cl >> 5, cc = cl & 31;
        *(bf16x8*)&v_t[(((size_t)s_local*H_DIM + h)*C_DIM + cc)*I_DIM + j0 + part*8] = d;
    }
}

// ---------------------------------------------------------------------------
// K56 v5: fused einsum + gate-mult + out-projection.
// Grid (2 ih, Sc/4 sg), 512 threads (8 waves), 1 block/CU.
// Wave (ms = wave>>1, kv = wave&1) owns s = sg*4+ms, i rows ih*192+kv*96..+96.
//   -> each staged Ws tile (12 KB) feeds 4 s (2x arithmetic intensity of v4);
//      V operand loaded straight to registers (per-lane 16B, 2-tile prefetch);
//      Ws pipeline is 3 deep with exact per-wave counted vmcnt (never 0
//      mid-loop).  Ws is row-major with seg-XOR swizzle (seg ^= (row>>1)&3):
//      inverse swizzle applied on the per-lane GLOBAL address (rule #21), so
//      staging stays 16-lines/instr coalesced and ds_read_b128 is 2-way (free).
// Per-wave per-tile VMEM: waves 0-3 stage 2 chunks, waves 4-7 stage 1 (n),
// plus 2 av loads -> steady-state wait vmcnt(2n+2) = 6/4.
// Epilogue gate/Wot loads are compiler-waited (vmcnt(0) once per h; data has
// already streamed in, cost ~latency once per h).
// Math identical to v4 (same fragment mapping / accumulation order).
// ---------------------------------------------------------------------------
__global__ __launch_bounds__(512, 2) void k56_einsum_proj(
    const short* __restrict__ w,     // [8][384][384]
    const short* __restrict__ v_t,   // [Sc][8][32][384]
    const short* __restrict__ gate,  // [Sc*384][256]
    const short* __restrict__ Wot,   // [64][256]
    float* __restrict__ out)         // [Sc*384][64]
{
    __shared__ alignas(16) short Ws[3][192*32];  // 3 x 12288 B, seg-swizzled
    __shared__ alignas(16) short Ob[8][32*40];   // wave-private, 20480 B
    const int tid = threadIdx.x;                 // total LDS 57344 B
    const int wave = tid >> 6, lane = tid & 63;
    const int fr = lane & 15, fq = lane >> 4;
    const int ibase = blockIdx.x * 192;   // i-half
    const int sg = blockIdx.y;            // s-group of 4
    const int ms = wave >> 1;             // s within group (0..3)
    const int kv = wave & 1;              // i-sub within half
    const int s  = sg*4 + ms;
    const int iw = kv * 96;               // wave's i-offset within half

    const short* vts = v_t + (size_t)s * H_DIM * C_DIM * I_DIM;

    // stage tile (h_,kt_) into Ws[buf]: chunks of 16 rows; wave stages chunk
    // `wave` (all) and chunk `8+wave` (waves 0-3).  Global src carries the
    // inverse seg-swizzle; LDS dest is linear (wave-uniform base + lane*16).
    auto stage = [&](int h_, int kt_, int buf) {
        const short* base = w + (size_t)h_*II + (size_t)kt_*32;
        {
            int row = wave*16 + (lane >> 2);
            int q = (lane & 3) ^ ((row >> 1) & 3);
            glds16(base + (size_t)(ibase + row)*I_DIM + q*8,
                   &Ws[buf][wave*16*32]);
        }
        if (wave < 4) {
            int row = (8 + wave)*16 + (lane >> 2);
            int q = (lane & 3) ^ ((row >> 1) & 3);
            glds16(base + (size_t)(ibase + row)*I_DIM + q*8,
                   &Ws[buf][(8 + wave)*16*32]);
        }
    };
    // V A-frags straight to regs: lane (fr,fq) = (c row, j seg)
    auto loadAv = [&](bf16x8* d, int h_, int kt_) {
        const short* vb = vts + (size_t)h_*(C_DIM*I_DIM) + kt_*32;
        d[0] = *(const bf16x8*)&vb[fr*I_DIM + fq*8];
        d[1] = *(const bf16x8*)&vb[(16 + fr)*I_DIM + fq*8];
    };

    f32x4 acc_o[6][4] = {};
    bf16x8 avs[3][2];

    // prologue: avs FIRST, then 3 staged tiles (issue order matters for vmcnt)
    loadAv(avs[0], 0, 0);
    loadAv(avs[1], 0, 1);
    __builtin_amdgcn_sched_barrier(0);
    stage(0, 0, 0);
    stage(0, 1, 1);
    stage(0, 2, 2);
    __builtin_amdgcn_sched_barrier(0);

#pragma unroll 1
    for (int h = 0; h < H_DIM; h++) {
        f32x4 acc_e[2][6] = {};
#pragma unroll
        for (int kt = 0; kt < 12; kt++) {
            const int cb = kt % 3;
            // --- wait: tile kt's Ws chunks + avs[cb] complete -------------
            // steady: newer-than-av(g) = st(g+1)[n] + av(g+1)[2] + st(g+2)[n]
            if (h == 0 && kt == 0) {
                if (wave < 4) asm volatile("s_waitcnt vmcnt(4)" ::: "memory");
                else          asm volatile("s_waitcnt vmcnt(2)" ::: "memory");
            } else if (h == 7 && kt == 10) {
                if (wave < 4) asm volatile("s_waitcnt vmcnt(4)" ::: "memory");
                else          asm volatile("s_waitcnt vmcnt(3)" ::: "memory");
            } else if (h == 7 && kt == 11) {
                asm volatile("s_waitcnt vmcnt(0)" ::: "memory");
            } else {
                if (wave < 4) asm volatile("s_waitcnt vmcnt(6)" ::: "memory");
                else          asm volatile("s_waitcnt vmcnt(4)" ::: "memory");
            }
            __builtin_amdgcn_s_barrier();
            __builtin_amdgcn_sched_barrier(0);

            // --- ds_read B-frags (swizzled row-major, 2-way = free) -------
            bf16x8 bwv[6];
#pragma unroll
            for (int ni = 0; ni < 6; ni++) {
                int row = iw + ni*16 + fr;
                bwv[ni] = *(const bf16x8*)
                    &Ws[cb][row*32 + ((fq ^ ((row >> 1) & 3)) << 3)];
            }
            // --- av prefetch for tile kt+2 (issue BEFORE stage glds) ------
            if (kt < 10)      loadAv(avs[(kt+2)%3], h, kt + 2);
            else if (h < 7)   loadAv(avs[(kt+2)%3], h + 1, kt - 10);
            __builtin_amdgcn_sched_barrier(0);

            asm volatile("s_waitcnt lgkmcnt(0)" ::: "memory");
            __builtin_amdgcn_sched_barrier(0);
            __builtin_amdgcn_s_barrier();       // all waves done reading cb
            __builtin_amdgcn_sched_barrier(0);

            // --- stage tile kt+3 into cb (3-tile flight) ------------------
            if (kt < 9)       stage(h, kt + 3, cb);
            else if (h < 7)   stage(h + 1, kt - 9, cb);
            __builtin_amdgcn_sched_barrier(0);

            __builtin_amdgcn_s_setprio(1);
#pragma unroll
            for (int mi = 0; mi < 2; mi++)
#pragma unroll
                for (int ni = 0; ni < 6; ni++)
                    acc_e[mi][ni] = __builtin_amdgcn_mfma_f32_16x16x32_bf16(
                        avs[cb][mi], bwv[ni], acc_e[mi][ni], 0, 0, 0);
            __builtin_amdgcn_s_setprio(0);
        }

        // --- per-h epilogue: gate mult + proj partial (wave-private Ob) ---
        // D layout: c = mi*16 + fq*4 + r, i = ni*16 + fr   [m89/m91]
        bf16x8 bw[4];
#pragma unroll
        for (int ni = 0; ni < 4; ni++)
            bw[ni] = *(const bf16x8*)&Wot[(ni*16 + fr)*HC + h*C_DIM + fq*8];
        short4 gv[2][6];
#pragma unroll
        for (int mi = 0; mi < 2; mi++)
#pragma unroll
        for (int ni = 0; ni < 6; ni++)
            gv[mi][ni] = *(const short4*)&gate[
                (size_t)(s*I_DIM + ibase + iw + ni*16 + fr)*HC
                + h*C_DIM + mi*16 + fq*4];

        short* myOb = Ob[wave];
#pragma unroll
        for (int p = 0; p < 3; p++) {       // 32 i-rows per pass
#pragma unroll
            for (int t = 0; t < 2; t++) {
                int ni = p*2 + t;
#pragma unroll
                for (int mi = 0; mi < 2; mi++) {
                    short4 g = gv[mi][ni];
                    short4 pk;
                    pk.x = f2bf(acc_e[mi][ni][0] * s2f(g.x));
                    pk.y = f2bf(acc_e[mi][ni][1] * s2f(g.y));
                    pk.z = f2bf(acc_e[mi][ni][2] * s2f(g.z));
                    pk.w = f2bf(acc_e[mi][ni][3] * s2f(g.w));
                    *(short4*)&myOb[(t*16 + fr)*40 + mi*16 + fq*4] = pk;
                }
            }
            bf16x8 ao[2];
#pragma unroll
            for (int t = 0; t < 2; t++)
                ao[t] = *(const bf16x8*)&myOb[(t*16 + fr)*40 + fq*8];
            __builtin_amdgcn_s_setprio(1);
#pragma unroll
            for (int t = 0; t < 2; t++)
#pragma unroll
                for (int ni = 0; ni < 4; ni++)
                    acc_o[p*2 + t][ni] = __builtin_amdgcn_mfma_f32_16x16x32_bf16(
                        ao[t], bw[ni], acc_o[p*2 + t][ni], 0, 0, 0);
            __builtin_amdgcn_s_setprio(0);
        }
    }

    // store out fp32 (this wave's 96 i rows for its s)
#pragma unroll
    for (int mi = 0; mi < 6; mi++)
#pragma unroll
    for (int ni = 0; ni < 4; ni++)
#pragma unroll
    for (int r = 0; r < 4; r++) {
        int i = ibase + iw + mi*16 + fq*4 + r;
        int n = ni*16 + fr;
        out[(size_t)(s*I_DIM + i)*CM + n] = acc_o[mi][ni][r];
    }
}

// ---------------------------------------------------------------------------
extern "C" void kernel_launch(void* const* d_in, const int* in_sizes, int n_in,
                              void* d_out, int out_size, void* d_ws, size_t ws_size,
                              hipStream_t stream)
{
    const float* msa  = (const float*)d_in[0];
    const float* pair = (const float*)d_in[1];
    const float* gm   = (const float*)d_in[2];
    const float* bm   = (const float*)d_in[3];
    const float* gp   = (const float*)d_in[4];
    const float* bp   = (const float*)d_in[5];
    const float* Wv   = (const float*)d_in[6];
    const float* Wb   = (const float*)d_in[7];
    const float* Wg   = (const float*)d_in[8];
    const float* Wo   = (const float*)d_in[9];

    // ws layout: w bf16 [0,2359296) | Wt [2359296,2424832) | Wot [2424832,2457600)
    //            region: bias fp32 overlay (dead after softmax), then v_t+gate
    char* ws = (char*)d_ws;
    short* w    = (short*)ws;
    short* Wt   = (short*)(ws + 2359296);
    short* Wot  = (short*)(ws + 2424832);
    char*  region = ws + 2457600;
    float* bias = (float*)region;

    // Largest S-chunk whose v_t+gate (Sc*393216 B) fits the region.
    size_t avail = (ws_size > 2457600u) ? (ws_size - 2457600u) : 0;
    int Sc = 8;
    const int scs[7] = {512, 256, 128, 64, 32, 16, 8};
    for (int i = 0; i < 7; i++) {
        size_t need = (size_t)scs[i] * 393216u;
        if (need < 4718592u) need = 4718592u;   // region also holds bias
        if (need <= avail) { Sc = scs[i]; break; }
    }
    const int NC = S_DIM / Sc;
    short* v_t  = (short*)region;                            // [Sc][8][32][384]
    short* gate = (short*)(region + (size_t)Sc*196608u);     // [Sc*384][256]

    k_pair_ln_bias<<<dim3(II/4), dim3(256), 0, stream>>>(pair, gp, bp, Wb, bias);
    k_prep_w<<<dim3(192), dim3(256), 0, stream>>>(Wv, Wg, Wo, Wt, Wot);
    k_softmax<<<dim3(I_DIM*H_DIM), dim3(I_DIM), 0, stream>>>(bias, w);

    for (int c = 0; c < NC; c++) {
        size_t in_off = (size_t)c * Sc * I_DIM * CM;

        // K4: fused LN + v/gate GEMM [Sc*384 x 64] @ [64 x 512]
        k4_ln_vgate<<<dim3(1, Sc*6, 1), dim3(256), 0, stream>>>(
            msa + in_off, gm, bm, Wt, v_t, gate);

        // K56 v5: fused einsum + gate + out-projection, (i-half, s-group4)
        k56_einsum_proj<<<dim3(2, Sc/4), dim3(512), 0, stream>>>(
            w, v_t, gate, Wot, (float*)d_out + in_off);
    }
}